// Round 9
// baseline (166.990 us; speedup 1.0000x reference)
//
#include <hip/hip_runtime.h>

// ---------------- problem constants ----------------
#define NB        8
#define NPB       120000
#define NPTS      (NB * NPB)       // 960000
#define MAX_PTS   10
#define MAX_VOX   40000
#define GX        704
#define GY        800
#define GZ        20

// R9: tagged-u64 claim + sweep-inverted resolution. Claim tables hold
// (lid<<32)|idx via plain 8B LWW stores (global_store_dwordx2 = single
// transaction, no tear) -> verification is tag-compare on the value itself:
// ONE random read per point (R7/R8 chained tbl-read -> lid32[w] verify).
// Claimer-vs-colliders resolution inverted into k_sweep over the 2MB slab
// (~3k live entries/batch): replaces ~830k per-claimer random probes with
// ~26k rare ops + coalesced sweep. Dual tables (A,B stored in k_init) keep
// deferral at ~2.6% => ~27k slab atomics total.
#define T0        (1 << 18)
#define T0MASK    (T0 - 1)

#define HC2       (1 << 15)        // slab (min-hash) slots per batch
#define HMASK2    (HC2 - 1)
#define NSLOT2    (NB * HC2)       // 262,144 slots, 2 MB

#define TILES     469              // ceil(120000 / 256)
#define TILES_PAD 512
#define MBCAP     8192             // per-batch multi list capacity (~800 expected)
#define MTILE     2048

#define EMPTY64   0xFFFFFFFFFFFFFFFFull

// output layout (flat float32)
#define OUT_VOX   0LL
#define OUT_NUM   12800000LL
#define OUT_COOR  13120000LL
#define OUT_GRID  14400000LL

__device__ __forceinline__ bool point_cell(const float* __restrict__ p,
                                           int& cx, int& cy, int& cz) {
    // must match numpy f32: floor((xyz - PC_MIN) / VSIZE)
    cx = (int)floorf((p[1] - 0.0f)   / 0.1f);
    cy = (int)floorf((p[2] - (-40.0f)) / 0.1f);
    cz = (int)floorf((p[3] - (-3.0f))  / 0.2f);
    return (cx >= 0) & (cx < GX) & (cy >= 0) & (cy < GY) & (cz >= 0) & (cz < GZ);
}

__device__ __forceinline__ unsigned hashA(int lid) {
    return (((unsigned)lid * 2654435761u) >> 14) & T0MASK;
}
__device__ __forceinline__ unsigned hashB(int lid) {
    return (((unsigned)lid * 0x9E3779B1u) >> 13) & T0MASK;
}
__device__ __forceinline__ unsigned slab_hash(int lid) {
    return (((unsigned)lid * 2654435761u) >> 17) & HMASK2;
}

// robin-hood atomicMin insert into the per-batch slab (min idx per cell).
// Slot values only decrease, entries only move forward, exactly one live
// entry per cell at settle; lookups probe home..first-EMPTY with no gaps.
__device__ __forceinline__ void slab_insert(unsigned long long* __restrict__ base,
                                            int lid, int idx) {
    unsigned long long key = ((unsigned long long)(unsigned)lid << 32)
                           | (unsigned long long)(unsigned)idx;
    unsigned h = slab_hash(lid);
    while (true) {
        unsigned long long oo = atomicMin(base + h, key);
        if (oo == EMPTY64) break;                  // filled empty slot
        if ((oo >> 32) == (key >> 32)) break;      // same cell: min folded
        if (oo > key) key = oo;                    // displaced foreign: carry forward
        h = (h + 1) & HMASK2;
    }
}

// settled-slab lookup (entry guaranteed present for callers here)
__device__ __forceinline__ unsigned slab_find(const unsigned long long* __restrict__ base,
                                              int lid) {
    unsigned h = slab_hash(lid);
    while (true) {
        unsigned long long cur = base[h];
        if ((unsigned)(cur >> 32) == (unsigned)lid) return (unsigned)cur;
        h = (h + 1) & HMASK2;
    }
}

// settled-table claimer lookup: returns claimer idx or 0xFFFFFFFF if deferred
__device__ __forceinline__ unsigned claimer_of(const unsigned long long* __restrict__ tA,
                                               const unsigned long long* __restrict__ tB,
                                               int b, int lid) {
    unsigned long long v = tA[(size_t)b * T0 + hashA(lid)];
    if ((unsigned)(v >> 32) == (unsigned)lid) return (unsigned)v;
    v = tB[(size_t)b * T0 + hashB(lid)];
    if ((unsigned)(v >> 32) == (unsigned)lid) return (unsigned)v;
    return 0xFFFFFFFFu;
}

// ---------------- K0: lid + dual tagged claim stores + slab init ----------------
// Claims are plain scattered u64 stores (posted, no round trip; 8B aligned
// single-instruction => no tear). Tables need NO init: every slot later read
// was written (readers only look up lids whose points stored there).
__global__ void k_init(const float* __restrict__ pts, float* __restrict__ out,
                       ulonglong2* __restrict__ slab2,
                       unsigned long long* __restrict__ tblA,
                       unsigned long long* __restrict__ tblB,
                       int* __restrict__ lid32, unsigned* __restrict__ mcount) {
    int b = blockIdx.x & 7;
    int idx = (blockIdx.x >> 3) * 256 + threadIdx.x;
    if (idx < NPB) {
        int g = b * NPB + idx;
        const float* p = pts + (long long)g * 5;
        int cx, cy, cz;
        if (point_cell(p, cx, cy, cz)) {
            int lid = (cz * GY + cy) * GX + cx;
            lid32[g] = lid;
            unsigned long long key = ((unsigned long long)(unsigned)lid << 32)
                                   | (unsigned long long)(unsigned)idx;
            tblA[(size_t)b * T0 + hashA(lid)] = key;     // LWW claims
            tblB[(size_t)b * T0 + hashB(lid)] = key;
        } else {
            lid32[g] = -1;
        }
    }
    int t = blockIdx.x * 256 + threadIdx.x;              // 960,512 threads
    if (t < NSLOT2 / 2) {
        ulonglong2 e2; e2.x = EMPTY64; e2.y = EMPTY64;
        slab2[t] = e2;                                   // 2 MB
    }
    if (t < NB) mcount[t * 16] = 0u;
    if (t == 0) {
        out[OUT_GRID + 0] = 704.f;
        out[OUT_GRID + 1] = 800.f;
        out[OUT_GRID + 2] = 20.f;
    }
}

// ---------------- K1: classify (1 random read); losers/colliders -> slab ----------------
// flag: 1 = provisional leader (claimer), 0 = everyone else.
// Tag-compare on the table value itself -- no dependent verify read.
__global__ void k_l0(const int* __restrict__ lid32,
                     const unsigned long long* __restrict__ tblA,
                     const unsigned long long* __restrict__ tblB,
                     unsigned char* __restrict__ flag,
                     unsigned long long* __restrict__ slabB) {
    int b = blockIdx.x & 7;
    int idx = (blockIdx.x >> 3) * 256 + threadIdx.x;
    if (idx >= NPB) return;
    int g = b * NPB + idx;
    int lid = lid32[g];
    if (lid < 0) { flag[g] = 0; return; }
    unsigned long long v = tblA[(size_t)b * T0 + hashA(lid)];   // settled
    if ((unsigned)(v >> 32) == (unsigned)lid) {                 // claimed at A
        if ((unsigned)v == (unsigned)idx) { flag[g] = 1; return; }
        flag[g] = 0;                                            // collider
        slab_insert(slabB + (size_t)b * HC2, lid, idx);
        return;
    }
    v = tblB[(size_t)b * T0 + hashB(lid)];                      // second chance
    if ((unsigned)(v >> 32) == (unsigned)lid) {
        if ((unsigned)v == (unsigned)idx) { flag[g] = 1; return; }
        flag[g] = 0;
        slab_insert(slabB + (size_t)b * HC2, lid, idx);
        return;
    }
    flag[g] = 0;                                                // deferred cell
    slab_insert(slabB + (size_t)b * HC2, lid, idx);
}

// ---------------- K2: sweep live slab entries; fix leadership flags ----------------
// One thread per slab slot (coalesced 2MB read; ~3k live/batch take the rare
// path). Entry (lid, smin): claimed cell -> if smin < claimer, demote claimer
// & promote smin; deferred cell -> promote smin. Unique writer per cell's
// flag bytes (one live entry per cell).
__global__ void k_sweep(const unsigned long long* __restrict__ slabB,
                        const unsigned long long* __restrict__ tblA,
                        const unsigned long long* __restrict__ tblB,
                        unsigned char* __restrict__ flag) {
    int s = blockIdx.x * 256 + threadIdx.x;            // 0..NSLOT2-1
    unsigned long long v = slabB[s];
    if (v == EMPTY64) return;
    int b = s >> 15;                                   // s / HC2
    int lid = (int)(unsigned)(v >> 32);
    unsigned smin = (unsigned)v;
    unsigned cl = claimer_of(tblA, tblB, b, lid);      // 0xFFFFFFFF if deferred
    if (cl == 0xFFFFFFFFu) {
        flag[b * NPB + (int)smin] = 1;                 // deferred: promote min
    } else if (smin < cl) {
        flag[b * NPB + (int)cl] = 0;                   // demote claimer
        flag[b * NPB + (int)smin] = 1;                 // promote true leader
    }                                                  // else claimer stays leader
}

// ---------------- K3: per-tile leader counts + mlist (rare slow path) ----------------
// 1 wave per 256-point tile; 4 points/lane (flag u32 + lid int4, coalesced).
// flag=0 & lid>=0 => multi-cell non-leader or deferred non-min (~3.4k/batch):
// resolve leader from settled slab/tables and append mlist.
__global__ void k_count(const unsigned* __restrict__ flag32, const int* __restrict__ lid32,
                        const unsigned long long* __restrict__ slabB,
                        const unsigned long long* __restrict__ tblA,
                        const unsigned long long* __restrict__ tblB,
                        int* __restrict__ tileSum, int2* __restrict__ mlist,
                        unsigned* __restrict__ mcount) {
    int w = blockIdx.x * 4 + ((int)threadIdx.x >> 6);  // 0..3751
    int lane = threadIdx.x & 63;
    int b = w & 7;
    int tile = w >> 3;
    int i = tile * 64 + lane;                          // u32-flag index within batch
    unsigned x = 0u;
    if (i < NPB / 4) {
        x = flag32[b * (NPB / 4) + i];
        int4 l4 = ((const int4*)lid32)[b * (NPB / 4) + i];
        #pragma unroll
        for (int k = 0; k < 4; k++) {
            int lk = (k == 0) ? l4.x : (k == 1) ? l4.y : (k == 2) ? l4.z : l4.w;
            if (((x >> (8 * k)) & 255u) == 0u && lk >= 0) {
                // rare: resolve true leader (entry guaranteed in slab)
                unsigned smin = slab_find(slabB + (size_t)b * HC2, lk);
                unsigned cl = claimer_of(tblA, tblB, b, lk);
                unsigned leader = (smin < cl) ? smin : cl;
                int idx = i * 4 + k;
                unsigned m = atomicAdd(&mcount[b * 16], 1u);
                if (m < MBCAP)
                    mlist[(size_t)b * MBCAP + m] = make_int2((int)leader, idx);
            }
        }
    }
    int s = (int)((x * 0x01010101u) >> 24);            // byte-sum (each byte 0/1)
    #pragma unroll
    for (int off = 32; off; off >>= 1) s += __shfl_down(s, off);
    if (lane == 0) tileSum[b * TILES_PAD + tile] = s;
}

// ---------------- K4: fused scans + leader full-row writes + slotOf ----------------
// Scan A: 469 tile sums (1.9 KB, L2-hot). Scan B: in-tile rank from flag.
// Full 160B rows, cached stores (contiguous ~35KB/tile, L2-combined; clean
// 58MB write confirmed by R8 counters).
__global__ void k_finish(const float* __restrict__ pts, const int* __restrict__ lid32,
                         const unsigned char* __restrict__ flag,
                         const int* __restrict__ tileSum,
                         float* __restrict__ out, unsigned short* __restrict__ slotOf) {
    int b = blockIdx.x & 7;
    int tile = blockIdx.x >> 3;
    int t = threadIdx.x;

    __shared__ int sc[256];
    __shared__ int soff[TILES_PAD];
    int v0 = (2 * t     < TILES) ? tileSum[b * TILES_PAD + 2 * t]     : 0;
    int v1 = (2 * t + 1 < TILES) ? tileSum[b * TILES_PAD + 2 * t + 1] : 0;
    int w = v0 + v1;
    sc[t] = w;
    __syncthreads();
    for (int off = 1; off < 256; off <<= 1) {
        int x = sc[t];
        if (t >= off) x += sc[t - off];
        __syncthreads();
        sc[t] = x;
        __syncthreads();
    }
    int e = sc[t] - w;
    soff[2 * t] = e;
    soff[2 * t + 1] = e + v0;
    __syncthreads();

    int idx = tile * 256 + t;
    int g = b * NPB + idx;
    int f = (idx < NPB) ? (int)flag[g] : 0;
    sc[t] = f;
    __syncthreads();
    for (int off = 1; off < 256; off <<= 1) {
        int x = sc[t];
        if (t >= off) x += sc[t - off];
        __syncthreads();
        sc[t] = x;
        __syncthreads();
    }
    int rank = sc[t] - f;                      // exclusive in-tile rank
    // no __syncthreads below this point

    if (idx >= NPB || !f) return;              // leaders only

    int slot = soff[tile] + rank;
    slotOf[g] = (unsigned short)(slot < 65535 ? slot : 65535);  // before clip!
    if (slot >= MAX_VOX) return;
    int lid = lid32[g];
    unsigned ul = (unsigned)lid;
    unsigned cx = ul % (unsigned)GX;
    unsigned tt = ul / (unsigned)GX;
    unsigned cy = tt % (unsigned)GY;
    unsigned cz = tt / (unsigned)GY;
    long long r = (long long)b * MAX_VOX + slot;
    ((float4*)(out + OUT_COOR))[r] = make_float4((float)b, (float)cz, (float)cy, (float)cx);
    out[OUT_NUM + r] = 1.f;                    // multi corrected by k_multi
    const float* p = pts + (long long)g * 5;
    float4* row = (float4*)(out + OUT_VOX) + (size_t)r * MAX_PTS;
    row[0] = make_float4(p[1], p[2], p[3], p[4]);
    float4 zf = make_float4(0.f, 0.f, 0.f, 0.f);
    #pragma unroll
    for (int i = 1; i < MAX_PTS; i++) row[i] = zf;
}

// ---------------- K5: rank + scatter multi-cell non-leaders; fix num ----------------
// mlist entries are (leaderIdx, idx), leader never in list; slot via slotOf.
__global__ void k_multi(const float* __restrict__ pts,
                        const int2* __restrict__ mlist, const unsigned* __restrict__ mcount,
                        const unsigned short* __restrict__ slotOf,
                        float* __restrict__ out) {
    int b = blockIdx.y;
    unsigned n = mcount[b * 16];
    if (n > MBCAP) n = MBCAP;
    unsigned t = blockIdx.x * blockDim.x + threadIdx.x;
    const int2* lst = mlist + (size_t)b * MBCAP;
    bool active = (t < n);
    int2 e = active ? lst[t] : make_int2(-1, -1);   // (leaderIdx, idx)
    int pos = 1;                                    // leader (not in list) is pos 0
    int same = 0;                                   // same-cell entries incl. self
    __shared__ int2 sm[MTILE];
    for (unsigned chunk = 0; chunk < n; chunk += MTILE) {
        unsigned m = n - chunk;
        if (m > MTILE) m = MTILE;
        for (unsigned i = threadIdx.x; i < m; i += 256)
            sm[i] = lst[chunk + i];
        __syncthreads();
        if (active) {
            #pragma unroll 4
            for (unsigned j = 0; j < m; j++) {
                int2 o = sm[j];
                if (o.x == e.x) { same++; if (o.y < e.y) pos++; }
            }
        }
        __syncthreads();
    }
    if (!active) return;
    int slot = (int)slotOf[(size_t)b * NPB + e.x];
    if (slot >= MAX_VOX) return;
    if (pos == 1) {                                 // smallest non-leader writes true count
        int cnt = same + 1;                         // + leader
        out[OUT_NUM + (long long)b * MAX_VOX + slot] =
            (float)(cnt < MAX_PTS ? cnt : MAX_PTS);
    }
    if (pos >= MAX_PTS) return;
    const float* p = pts + ((long long)b * NPB + e.y) * 5;
    ((float4*)(out + OUT_VOX))[(long long)(b * MAX_VOX + slot) * MAX_PTS + pos] =
        make_float4(p[1], p[2], p[3], p[4]);
}

extern "C" void kernel_launch(void* const* d_in, const int* in_sizes, int n_in,
                              void* d_out, int out_size, void* d_ws, size_t ws_size,
                              hipStream_t stream) {
    const float* pts = (const float*)d_in[0];
    float* out = (float*)d_out;

    char* w = (char*)d_ws;
    unsigned long long* tblA = (unsigned long long*)w; w += (size_t)NB * T0 * 8; // 16 MB
    unsigned long long* tblB = (unsigned long long*)w; w += (size_t)NB * T0 * 8; // 16 MB
    unsigned long long* slabB = (unsigned long long*)w;
    w += (size_t)NSLOT2 * 8;                                               // 2 MB
    int2* mlist = (int2*)w;  w += (size_t)NB * MBCAP * 8;                  // 0.5 MB
    int* lid32 = (int*)w;    w += (size_t)NPTS * 4;                        // 3.84 MB
    int* tileSum = (int*)w;  w += (size_t)NB * TILES_PAD * 4;              // 16 KB
    unsigned* mcount = (unsigned*)w; w += (size_t)NB * 16 * 4;             // 512 B
    unsigned short* slotOf = (unsigned short*)w; w += (size_t)NPTS * 2;    // 1.92 MB
    unsigned char* flag = (unsigned char*)w;  w += (size_t)NPTS;           // 0.96 MB

    const int PB = TILES * NB;      // 3752 blocks for per-point kernels
    k_init<<<dim3(PB), dim3(256), 0, stream>>>(pts, out, (ulonglong2*)slabB,
                                               tblA, tblB, lid32, mcount);
    k_l0<<<dim3(PB), dim3(256), 0, stream>>>(lid32, tblA, tblB, flag, slabB);
    k_sweep<<<dim3(NSLOT2 / 256), dim3(256), 0, stream>>>(slabB, tblA, tblB, flag);
    k_count<<<dim3(TILES * NB / 4), dim3(256), 0, stream>>>((const unsigned*)flag, lid32,
                                                            slabB, tblA, tblB,
                                                            tileSum, mlist, mcount);
    k_finish<<<dim3(PB), dim3(256), 0, stream>>>(pts, lid32, flag, tileSum, out, slotOf);
    k_multi<<<dim3(MBCAP / 256, NB), dim3(256), 0, stream>>>(pts, mlist, mcount, slotOf, out);
}

// Round 10
// 156.485 us; speedup vs baseline: 1.0671x; 1.0671x over previous
//
#include <hip/hip_runtime.h>

// ---------------- problem constants ----------------
#define NB        8
#define NPB       120000
#define NPTS      (NB * NPB)       // 960000
#define MAX_PTS   10
#define MAX_VOX   40000
#define GX        704
#define GY        800
#define GZ        20

// R10 = best-of(R7 front-end, R9 back-end).
// Front-end (R7, measured fastest claim): single u32 LWW claim table tbl0
// (1 MB/batch) stored in k_init; verify = tbl read + lid32[w] read (both
// L2-resident; R9 proved "1 tagged read" costs MORE via doubled scatter
// stores + 4x table footprint). Losers (~16%) re-claim at tbl1 (u32, 2^16).
// Losers of both (~2.6%) defer. Colliders + deferred atomicMin into slab
// (~27k atomics total).
// Back-end (R9): k_sweep inverts claimer-vs-min resolution over the 2 MB
// slab (~3.4k live entries) -- replaces R7's k_phase2 full pass (~710k
// random probes) with a coalesced sweep + ~4k scattered flag fixes.
// k_count builds mlist (slow path, ~3.9k/batch); k_finish is leader-only.
#define T0        (1 << 18)
#define T0MASK    (T0 - 1)
#define T1        (1 << 16)
#define T1MASK    (T1 - 1)

#define HC2       (1 << 15)        // slab (min-hash) slots per batch
#define HMASK2    (HC2 - 1)
#define NSLOT2    (NB * HC2)       // 262,144 slots, 2 MB

#define TILES     469              // ceil(120000 / 256)
#define TILES_PAD 512
#define MBCAP     8192             // per-batch multi list capacity (~800 expected)
#define MTILE     2048

#define EMPTY64   0xFFFFFFFFFFFFFFFFull

// output layout (flat float32)
#define OUT_VOX   0LL
#define OUT_NUM   12800000LL
#define OUT_COOR  13120000LL
#define OUT_GRID  14400000LL

__device__ __forceinline__ bool point_cell(const float* __restrict__ p,
                                           int& cx, int& cy, int& cz) {
    // must match numpy f32: floor((xyz - PC_MIN) / VSIZE)
    cx = (int)floorf((p[1] - 0.0f)   / 0.1f);
    cy = (int)floorf((p[2] - (-40.0f)) / 0.1f);
    cz = (int)floorf((p[3] - (-3.0f))  / 0.2f);
    return (cx >= 0) & (cx < GX) & (cy >= 0) & (cy < GY) & (cz >= 0) & (cz < GZ);
}

__device__ __forceinline__ unsigned hash0(int lid) {
    return (((unsigned)lid * 2654435761u) >> 14) & T0MASK;
}
__device__ __forceinline__ unsigned hash1(int lid) {
    return (((unsigned)lid * 0x9E3779B1u) >> 16) & T1MASK;
}
__device__ __forceinline__ unsigned slab_hash(int lid) {
    return (((unsigned)lid * 2654435761u) >> 17) & HMASK2;
}

// robin-hood atomicMin insert into the per-batch slab (min idx per cell).
__device__ __forceinline__ void slab_insert(unsigned long long* __restrict__ base,
                                            int lid, int idx) {
    unsigned long long key = ((unsigned long long)(unsigned)lid << 32)
                           | (unsigned long long)(unsigned)idx;
    unsigned h = slab_hash(lid);
    while (true) {
        unsigned long long oo = atomicMin(base + h, key);
        if (oo == EMPTY64) break;                  // filled empty slot
        if ((oo >> 32) == (key >> 32)) break;      // same cell: min folded
        if (oo > key) key = oo;                    // displaced foreign: carry forward
        h = (h + 1) & HMASK2;
    }
}

// settled-slab lookup (entry guaranteed present for callers here)
__device__ __forceinline__ unsigned slab_find(const unsigned long long* __restrict__ base,
                                              int lid) {
    unsigned h = slab_hash(lid);
    while (true) {
        unsigned long long cur = base[h];
        if ((unsigned)(cur >> 32) == (unsigned)lid) return (unsigned)cur;
        h = (h + 1) & HMASK2;
    }
}

// settled claimer lookup. SAFETY ORDER: read tbl0 first (every valid point
// stored there -> slot written this iteration, value < NPB); only if the cell
// lost A do we read tbl1 (its points then stored tbl1 in k_l0). Never reads
// an unwritten (poison) slot.
__device__ __forceinline__ unsigned claimer_of(const unsigned* __restrict__ tbl0,
                                               const unsigned* __restrict__ tbl1,
                                               const int* __restrict__ lid32,
                                               int b, int lid) {
    unsigned w = tbl0[b * T0 + hash0(lid)];
    if (lid32[b * NPB + (int)w] == lid) return w;
    w = tbl1[b * T1 + hash1(lid)];
    if (lid32[b * NPB + (int)w] == lid) return w;
    return 0xFFFFFFFFu;                              // deferred cell
}

// ---------------- K0: lid + L0 claim store + slab init + mcount + grid ----------------
// One scattered 4B store per valid point (posted). tbl0/tbl1 need NO init:
// every slot later read was written this iteration (readers only look up
// slots their own cell stored to, in A-then-B order).
__global__ void k_init(const float* __restrict__ pts, float* __restrict__ out,
                       ulonglong2* __restrict__ slab2, unsigned* __restrict__ tbl0,
                       int* __restrict__ lid32, unsigned* __restrict__ mcount) {
    int b = blockIdx.x & 7;
    int idx = (blockIdx.x >> 3) * 256 + threadIdx.x;
    if (idx < NPB) {
        int g = b * NPB + idx;
        const float* p = pts + (long long)g * 5;
        int cx, cy, cz;
        if (point_cell(p, cx, cy, cz)) {
            int lid = (cz * GY + cy) * GX + cx;
            lid32[g] = lid;
            tbl0[b * T0 + hash0(lid)] = (unsigned)idx;   // LWW claim
        } else {
            lid32[g] = -1;
        }
    }
    int t = blockIdx.x * 256 + threadIdx.x;              // 960,512 threads
    if (t < NSLOT2 / 2) {
        ulonglong2 e2; e2.x = EMPTY64; e2.y = EMPTY64;
        slab2[t] = e2;                                   // 2 MB
    }
    if (t < NB) mcount[t * 16] = 0u;
    if (t == 0) {
        out[OUT_GRID + 0] = 704.f;
        out[OUT_GRID + 1] = 800.f;
        out[OUT_GRID + 2] = 20.f;
    }
}

// ---------------- K1: classify L0; losers -> L1 claim store; colliders -> slab ----------------
// flag: 1 = provisional leader (claimer), 2 = pending L1, 0 = else.
__global__ void k_l0(const int* __restrict__ lid32, const unsigned* __restrict__ tbl0,
                     unsigned* __restrict__ tbl1, unsigned char* __restrict__ flag,
                     unsigned long long* __restrict__ slabB) {
    int b = blockIdx.x & 7;
    int idx = (blockIdx.x >> 3) * 256 + threadIdx.x;
    if (idx >= NPB) return;
    int g = b * NPB + idx;
    int lid = lid32[g];
    if (lid < 0) { flag[g] = 0; return; }
    unsigned w = tbl0[b * T0 + hash0(lid)];              // settled; own cell stored
    if (lid32[b * NPB + (int)w] == lid) {                // cell claimed at A
        if (w == (unsigned)idx) { flag[g] = 1; return; } // claimer
        flag[g] = 0;                                     // collider
        slab_insert(slabB + (size_t)b * HC2, lid, idx);
        return;
    }
    tbl1[b * T1 + hash1(lid)] = (unsigned)idx;           // retry at L1 (~16%)
    flag[g] = 2;
}

// ---------------- K2: classify L1; colliders + deferred -> slab ----------------
__global__ void k_l1(const int* __restrict__ lid32, const unsigned* __restrict__ tbl1,
                     unsigned char* __restrict__ flag,
                     unsigned long long* __restrict__ slabB) {
    int b = blockIdx.x & 7;
    int idx = (blockIdx.x >> 3) * 256 + threadIdx.x;
    if (idx >= NPB) return;
    int g = b * NPB + idx;
    if (flag[g] != 2) return;                            // L1-pending only
    int lid = lid32[g];
    unsigned w = tbl1[b * T1 + hash1(lid)];              // own cell stored here
    if (lid32[b * NPB + (int)w] == lid) {                // claimed at B
        if (w == (unsigned)idx) { flag[g] = 1; return; }
        flag[g] = 0;
        slab_insert(slabB + (size_t)b * HC2, lid, idx);
        return;
    }
    flag[g] = 0;                                         // deferred cell (~2.6%)
    slab_insert(slabB + (size_t)b * HC2, lid, idx);
}

// ---------------- K3: sweep live slab entries; finalize leadership flags ----------------
// One thread per slab slot (coalesced 2 MB; ~3.4k live/batch take rare path).
// claimed cell: if slab min < claimer -> demote claimer, promote min.
// deferred cell (no claimer): promote min. Unique flag-writer per cell.
__global__ void k_sweep(const unsigned long long* __restrict__ slabB,
                        const unsigned* __restrict__ tbl0, const unsigned* __restrict__ tbl1,
                        const int* __restrict__ lid32, unsigned char* __restrict__ flag) {
    int s = blockIdx.x * 256 + threadIdx.x;            // 0..NSLOT2-1
    unsigned long long v = slabB[s];
    if (v == EMPTY64) return;
    int b = s >> 15;                                   // s / HC2
    int lid = (int)(unsigned)(v >> 32);
    unsigned smin = (unsigned)v;
    unsigned cl = claimer_of(tbl0, tbl1, lid32, b, lid);
    if (cl == 0xFFFFFFFFu) {
        flag[b * NPB + (int)smin] = 1;                 // deferred: promote min
    } else if (smin < cl) {
        flag[b * NPB + (int)cl] = 0;                   // demote claimer
        flag[b * NPB + (int)smin] = 1;                 // promote true leader
    }                                                  // else claimer stays leader
}

// ---------------- K4: per-tile leader counts + mlist (rare slow path) ----------------
// 1 wave per 256-point tile; 4 points/lane (flag u32 + lid int4, coalesced).
// flag=0 & lid>=0 => valid non-leader (~3.9k/batch): resolve true leader
// from settled slab/tables, append mlist.
__global__ void k_count(const unsigned* __restrict__ flag32, const int* __restrict__ lid32,
                        const unsigned long long* __restrict__ slabB,
                        const unsigned* __restrict__ tbl0, const unsigned* __restrict__ tbl1,
                        int* __restrict__ tileSum, int2* __restrict__ mlist,
                        unsigned* __restrict__ mcount) {
    int w = blockIdx.x * 4 + ((int)threadIdx.x >> 6);  // 0..3751
    int lane = threadIdx.x & 63;
    int b = w & 7;
    int tile = w >> 3;
    int i = tile * 64 + lane;                          // u32-flag index within batch
    unsigned x = 0u;
    if (i < NPB / 4) {
        x = flag32[b * (NPB / 4) + i];
        int4 l4 = ((const int4*)lid32)[b * (NPB / 4) + i];
        #pragma unroll
        for (int k = 0; k < 4; k++) {
            int lk = (k == 0) ? l4.x : (k == 1) ? l4.y : (k == 2) ? l4.z : l4.w;
            if (((x >> (8 * k)) & 255u) == 0u && lk >= 0) {
                unsigned smin = slab_find(slabB + (size_t)b * HC2, lk);
                unsigned cl = claimer_of(tbl0, tbl1, lid32, b, lk);
                unsigned leader = (smin < cl) ? smin : cl;
                int idx = i * 4 + k;
                unsigned m = atomicAdd(&mcount[b * 16], 1u);
                if (m < MBCAP)
                    mlist[(size_t)b * MBCAP + m] = make_int2((int)leader, idx);
            }
        }
    }
    int s = (int)((x * 0x01010101u) >> 24);            // byte-sum (each byte 0/1)
    #pragma unroll
    for (int off = 32; off; off >>= 1) s += __shfl_down(s, off);
    if (lane == 0) tileSum[b * TILES_PAD + tile] = s;
}

// ---------------- K5: fused scans + leader full-row writes + slotOf ----------------
// Full 160B rows, cached stores (contiguous ~35KB/tile regions, L2-combined;
// clean 58 MB write confirmed by R8 counters).
__global__ void k_finish(const float* __restrict__ pts, const int* __restrict__ lid32,
                         const unsigned char* __restrict__ flag,
                         const int* __restrict__ tileSum,
                         float* __restrict__ out, unsigned short* __restrict__ slotOf) {
    int b = blockIdx.x & 7;
    int tile = blockIdx.x >> 3;
    int t = threadIdx.x;

    __shared__ int sc[256];
    __shared__ int soff[TILES_PAD];
    int v0 = (2 * t     < TILES) ? tileSum[b * TILES_PAD + 2 * t]     : 0;
    int v1 = (2 * t + 1 < TILES) ? tileSum[b * TILES_PAD + 2 * t + 1] : 0;
    int w = v0 + v1;
    sc[t] = w;
    __syncthreads();
    for (int off = 1; off < 256; off <<= 1) {
        int x = sc[t];
        if (t >= off) x += sc[t - off];
        __syncthreads();
        sc[t] = x;
        __syncthreads();
    }
    int e = sc[t] - w;
    soff[2 * t] = e;
    soff[2 * t + 1] = e + v0;
    __syncthreads();

    int idx = tile * 256 + t;
    int g = b * NPB + idx;
    int f = (idx < NPB) ? (int)flag[g] : 0;
    sc[t] = f;
    __syncthreads();
    for (int off = 1; off < 256; off <<= 1) {
        int x = sc[t];
        if (t >= off) x += sc[t - off];
        __syncthreads();
        sc[t] = x;
        __syncthreads();
    }
    int rank = sc[t] - f;                      // exclusive in-tile rank
    // no __syncthreads below this point

    if (idx >= NPB || !f) return;              // leaders only

    int slot = soff[tile] + rank;
    slotOf[g] = (unsigned short)(slot < 65535 ? slot : 65535);  // before clip!
    if (slot >= MAX_VOX) return;
    int lid = lid32[g];
    unsigned ul = (unsigned)lid;
    unsigned cx = ul % (unsigned)GX;
    unsigned tt = ul / (unsigned)GX;
    unsigned cy = tt % (unsigned)GY;
    unsigned cz = tt / (unsigned)GY;
    long long r = (long long)b * MAX_VOX + slot;
    ((float4*)(out + OUT_COOR))[r] = make_float4((float)b, (float)cz, (float)cy, (float)cx);
    out[OUT_NUM + r] = 1.f;                    // multi corrected by k_multi
    const float* p = pts + (long long)g * 5;
    float4* row = (float4*)(out + OUT_VOX) + (size_t)r * MAX_PTS;
    row[0] = make_float4(p[1], p[2], p[3], p[4]);
    float4 zf = make_float4(0.f, 0.f, 0.f, 0.f);
    #pragma unroll
    for (int i = 1; i < MAX_PTS; i++) row[i] = zf;
}

// ---------------- K6: rank + scatter multi-cell non-leaders; fix num ----------------
__global__ void k_multi(const float* __restrict__ pts,
                        const int2* __restrict__ mlist, const unsigned* __restrict__ mcount,
                        const unsigned short* __restrict__ slotOf,
                        float* __restrict__ out) {
    int b = blockIdx.y;
    unsigned n = mcount[b * 16];
    if (n > MBCAP) n = MBCAP;
    unsigned t = blockIdx.x * blockDim.x + threadIdx.x;
    const int2* lst = mlist + (size_t)b * MBCAP;
    bool active = (t < n);
    int2 e = active ? lst[t] : make_int2(-1, -1);   // (leaderIdx, idx)
    int pos = 1;                                    // leader (not in list) is pos 0
    int same = 0;                                   // same-cell entries incl. self
    __shared__ int2 sm[MTILE];
    for (unsigned chunk = 0; chunk < n; chunk += MTILE) {
        unsigned m = n - chunk;
        if (m > MTILE) m = MTILE;
        for (unsigned i = threadIdx.x; i < m; i += 256)
            sm[i] = lst[chunk + i];
        __syncthreads();
        if (active) {
            #pragma unroll 4
            for (unsigned j = 0; j < m; j++) {
                int2 o = sm[j];
                if (o.x == e.x) { same++; if (o.y < e.y) pos++; }
            }
        }
        __syncthreads();
    }
    if (!active) return;
    int slot = (int)slotOf[(size_t)b * NPB + e.x];
    if (slot >= MAX_VOX) return;
    if (pos == 1) {                                 // smallest non-leader writes true count
        int cnt = same + 1;                         // + leader
        out[OUT_NUM + (long long)b * MAX_VOX + slot] =
            (float)(cnt < MAX_PTS ? cnt : MAX_PTS);
    }
    if (pos >= MAX_PTS) return;
    const float* p = pts + ((long long)b * NPB + e.y) * 5;
    ((float4*)(out + OUT_VOX))[(long long)(b * MAX_VOX + slot) * MAX_PTS + pos] =
        make_float4(p[1], p[2], p[3], p[4]);
}

extern "C" void kernel_launch(void* const* d_in, const int* in_sizes, int n_in,
                              void* d_out, int out_size, void* d_ws, size_t ws_size,
                              hipStream_t stream) {
    const float* pts = (const float*)d_in[0];
    float* out = (float*)d_out;

    char* w = (char*)d_ws;
    unsigned* tbl0 = (unsigned*)w;            w += (size_t)NB * T0 * 4;    // 8 MB (no init)
    unsigned* tbl1 = (unsigned*)w;            w += (size_t)NB * T1 * 4;    // 2 MB (no init)
    unsigned long long* slabB = (unsigned long long*)w;
    w += (size_t)NSLOT2 * 8;                                               // 2 MB
    int2* mlist = (int2*)w;  w += (size_t)NB * MBCAP * 8;                  // 0.5 MB
    int* lid32 = (int*)w;    w += (size_t)NPTS * 4;                        // 3.84 MB
    int* tileSum = (int*)w;  w += (size_t)NB * TILES_PAD * 4;              // 16 KB
    unsigned* mcount = (unsigned*)w; w += (size_t)NB * 16 * 4;             // 512 B
    unsigned short* slotOf = (unsigned short*)w; w += (size_t)NPTS * 2;    // 1.92 MB
    unsigned char* flag = (unsigned char*)w;  w += (size_t)NPTS;           // 0.96 MB

    const int PB = TILES * NB;      // 3752 blocks for per-point kernels
    k_init<<<dim3(PB), dim3(256), 0, stream>>>(pts, out, (ulonglong2*)slabB,
                                               tbl0, lid32, mcount);
    k_l0<<<dim3(PB), dim3(256), 0, stream>>>(lid32, tbl0, tbl1, flag, slabB);
    k_l1<<<dim3(PB), dim3(256), 0, stream>>>(lid32, tbl1, flag, slabB);
    k_sweep<<<dim3(NSLOT2 / 256), dim3(256), 0, stream>>>(slabB, tbl0, tbl1, lid32, flag);
    k_count<<<dim3(TILES * NB / 4), dim3(256), 0, stream>>>((const unsigned*)flag, lid32,
                                                            slabB, tbl0, tbl1,
                                                            tileSum, mlist, mcount);
    k_finish<<<dim3(PB), dim3(256), 0, stream>>>(pts, lid32, flag, tileSum, out, slotOf);
    k_multi<<<dim3(MBCAP / 256, NB), dim3(256), 0, stream>>>(pts, mlist, mcount, slotOf, out);
}

// Round 11
// 156.103 us; speedup vs baseline: 1.0697x; 1.0024x over previous
//
#include <hip/hip_runtime.h>

// ---------------- problem constants ----------------
#define NB        8
#define NPB       120000
#define NPTS      (NB * NPB)       // 960000
#define MAX_PTS   10
#define MAX_VOX   40000
#define GX        704
#define GY        800
#define GZ        20

// R11 = R10 consolidated: single-level claim (tbl0 2^19/batch), no tbl1/k_l1.
// Cells that lose their LWW slot (~9% at load 0.197) defer straight to the
// slab (deferred cells are ~all single-point, so slab atomics only +51k and
// mlist stays ~520/batch). 6 dispatches:
//   k_init  : lid + LWW claim store + slab init
//   k_l0    : classify (tbl read + L2 verify); colliders+deferred -> slab
//   k_sweep : coalesced 2MB slab sweep fixes flags (~3.9k rare ops)
//   k_count : tile leader counts + mlist slow path
//   k_finish: shuffle-scan (2 barriers, was 32) + leader full-row writes
//   k_multi : rank + scatter multi-cell non-leaders
#define T0        (1 << 19)
#define T0MASK    (T0 - 1)

#define HC2       (1 << 15)        // slab (min-hash) slots per batch
#define HMASK2    (HC2 - 1)
#define NSLOT2    (NB * HC2)       // 262,144 slots, 2 MB

#define TILES     469              // ceil(120000 / 256)
#define TILES_PAD 512
#define MBCAP     8192             // per-batch multi list capacity (~520 expected)
#define MTILE     2048

#define EMPTY64   0xFFFFFFFFFFFFFFFFull

// output layout (flat float32)
#define OUT_VOX   0LL
#define OUT_NUM   12800000LL
#define OUT_COOR  13120000LL
#define OUT_GRID  14400000LL

__device__ __forceinline__ bool point_cell(const float* __restrict__ p,
                                           int& cx, int& cy, int& cz) {
    // must match numpy f32: floor((xyz - PC_MIN) / VSIZE)
    cx = (int)floorf((p[1] - 0.0f)   / 0.1f);
    cy = (int)floorf((p[2] - (-40.0f)) / 0.1f);
    cz = (int)floorf((p[3] - (-3.0f))  / 0.2f);
    return (cx >= 0) & (cx < GX) & (cy >= 0) & (cy < GY) & (cz >= 0) & (cz < GZ);
}

__device__ __forceinline__ unsigned hash0(int lid) {
    return (((unsigned)lid * 2654435761u) >> 13) & T0MASK;
}
__device__ __forceinline__ unsigned slab_hash(int lid) {
    return (((unsigned)lid * 2654435761u) >> 17) & HMASK2;
}

// robin-hood atomicMin insert into the per-batch slab (min idx per cell).
__device__ __forceinline__ void slab_insert(unsigned long long* __restrict__ base,
                                            int lid, int idx) {
    unsigned long long key = ((unsigned long long)(unsigned)lid << 32)
                           | (unsigned long long)(unsigned)idx;
    unsigned h = slab_hash(lid);
    while (true) {
        unsigned long long oo = atomicMin(base + h, key);
        if (oo == EMPTY64) break;                  // filled empty slot
        if ((oo >> 32) == (key >> 32)) break;      // same cell: min folded
        if (oo > key) key = oo;                    // displaced foreign: carry forward
        h = (h + 1) & HMASK2;
    }
}

// settled-slab lookup (entry guaranteed present for callers here)
__device__ __forceinline__ unsigned slab_find(const unsigned long long* __restrict__ base,
                                              int lid) {
    unsigned h = slab_hash(lid);
    while (true) {
        unsigned long long cur = base[h];
        if ((unsigned)(cur >> 32) == (unsigned)lid) return (unsigned)cur;
        h = (h + 1) & HMASK2;
    }
}

// settled claimer lookup. The slot was written this iteration (our cell's
// points stored there), so w < NPB always; verify via L2-resident lid32.
__device__ __forceinline__ unsigned claimer_of(const unsigned* __restrict__ tbl0,
                                               const int* __restrict__ lid32,
                                               int b, int lid) {
    unsigned w = tbl0[(size_t)b * T0 + hash0(lid)];
    if (lid32[b * NPB + (int)w] == lid) return w;
    return 0xFFFFFFFFu;                              // deferred cell
}

// exclusive 256-thread block scan via 64-wide shuffle + 4-wave combine.
// ONE barrier (caller provides a later barrier before LDS results are read).
__device__ __forceinline__ int block_scan_excl(int v, int t, int* wsum) {
    int lane = t & 63, wv = t >> 6;
    int x = v;
    #pragma unroll
    for (int d = 1; d < 64; d <<= 1) {
        int y = __shfl_up(x, d);
        if (lane >= d) x += y;
    }                                              // inclusive within wave
    if (lane == 63) wsum[wv] = x;
    __syncthreads();
    int base = 0;
    #pragma unroll
    for (int wj = 0; wj < 3; wj++) if (wj < wv) base += wsum[wj];
    return base + x - v;                           // exclusive over block
}

// ---------------- K0: lid + LWW claim store + slab init + mcount + grid ----------------
// One scattered 4B store per valid point (posted, no round trip). tbl0 needs
// NO init: every slot later read was written this iteration.
__global__ void k_init(const float* __restrict__ pts, float* __restrict__ out,
                       ulonglong2* __restrict__ slab2, unsigned* __restrict__ tbl0,
                       int* __restrict__ lid32, unsigned* __restrict__ mcount) {
    int b = blockIdx.x & 7;
    int idx = (blockIdx.x >> 3) * 256 + threadIdx.x;
    if (idx < NPB) {
        int g = b * NPB + idx;
        const float* p = pts + (long long)g * 5;
        int cx, cy, cz;
        if (point_cell(p, cx, cy, cz)) {
            int lid = (cz * GY + cy) * GX + cx;
            lid32[g] = lid;
            tbl0[(size_t)b * T0 + hash0(lid)] = (unsigned)idx;   // LWW claim
        } else {
            lid32[g] = -1;
        }
    }
    int t = blockIdx.x * 256 + threadIdx.x;              // 960,512 threads
    if (t < NSLOT2 / 2) {
        ulonglong2 e2; e2.x = EMPTY64; e2.y = EMPTY64;
        slab2[t] = e2;                                   // 2 MB
    }
    if (t < NB) mcount[t * 16] = 0u;
    if (t == 0) {
        out[OUT_GRID + 0] = 704.f;
        out[OUT_GRID + 1] = 800.f;
        out[OUT_GRID + 2] = 20.f;
    }
}

// ---------------- K1: classify; colliders + deferred -> slab ----------------
// flag: 1 = provisional leader (claimer), 0 = everyone else.
__global__ void k_l0(const int* __restrict__ lid32, const unsigned* __restrict__ tbl0,
                     unsigned char* __restrict__ flag,
                     unsigned long long* __restrict__ slabB) {
    int b = blockIdx.x & 7;
    int idx = (blockIdx.x >> 3) * 256 + threadIdx.x;
    if (idx >= NPB) return;
    int g = b * NPB + idx;
    int lid = lid32[g];
    if (lid < 0) { flag[g] = 0; return; }
    unsigned w = tbl0[(size_t)b * T0 + hash0(lid)];      // settled; own cell stored
    if (lid32[b * NPB + (int)w] == lid) {                // cell claimed
        if (w == (unsigned)idx) { flag[g] = 1; return; } // claimer
        flag[g] = 0;                                     // collider (~480/batch)
        slab_insert(slabB + (size_t)b * HC2, lid, idx);
        return;
    }
    flag[g] = 0;                                         // deferred cell (~9%)
    slab_insert(slabB + (size_t)b * HC2, lid, idx);
}

// ---------------- K2: sweep live slab entries; finalize leadership flags ----------------
// One thread per slab slot (coalesced 2 MB; ~9.8k live/batch take rare path).
// claimed cell: if slab min < claimer -> demote claimer, promote min.
// deferred cell (no claimer): promote min. Unique flag-writer per cell.
__global__ void k_sweep(const unsigned long long* __restrict__ slabB,
                        const unsigned* __restrict__ tbl0,
                        const int* __restrict__ lid32, unsigned char* __restrict__ flag) {
    int s = blockIdx.x * 256 + threadIdx.x;            // 0..NSLOT2-1
    unsigned long long v = slabB[s];
    if (v == EMPTY64) return;
    int b = s >> 15;                                   // s / HC2
    int lid = (int)(unsigned)(v >> 32);
    unsigned smin = (unsigned)v;
    unsigned cl = claimer_of(tbl0, lid32, b, lid);
    if (cl == 0xFFFFFFFFu) {
        flag[b * NPB + (int)smin] = 1;                 // deferred: promote min
    } else if (smin < cl) {
        flag[b * NPB + (int)cl] = 0;                   // demote claimer
        flag[b * NPB + (int)smin] = 1;                 // promote true leader
    }                                                  // else claimer stays leader
}

// ---------------- K3: per-tile leader counts + mlist (rare slow path) ----------------
// 1 wave per 256-point tile; 4 points/lane (flag u32 + lid int4, coalesced).
// flag=0 & lid>=0 => valid non-leader (~520/batch): resolve true leader from
// settled slab/table, append mlist.
__global__ void k_count(const unsigned* __restrict__ flag32, const int* __restrict__ lid32,
                        const unsigned long long* __restrict__ slabB,
                        const unsigned* __restrict__ tbl0,
                        int* __restrict__ tileSum, int2* __restrict__ mlist,
                        unsigned* __restrict__ mcount) {
    int w = blockIdx.x * 4 + ((int)threadIdx.x >> 6);  // 0..3751
    int lane = threadIdx.x & 63;
    int b = w & 7;
    int tile = w >> 3;
    int i = tile * 64 + lane;                          // u32-flag index within batch
    unsigned x = 0u;
    if (i < NPB / 4) {
        x = flag32[b * (NPB / 4) + i];
        int4 l4 = ((const int4*)lid32)[b * (NPB / 4) + i];
        #pragma unroll
        for (int k = 0; k < 4; k++) {
            int lk = (k == 0) ? l4.x : (k == 1) ? l4.y : (k == 2) ? l4.z : l4.w;
            if (((x >> (8 * k)) & 255u) == 0u && lk >= 0) {
                unsigned smin = slab_find(slabB + (size_t)b * HC2, lk);
                unsigned cl = claimer_of(tbl0, lid32, b, lk);
                unsigned leader = (smin < cl) ? smin : cl;
                int idx = i * 4 + k;
                unsigned m = atomicAdd(&mcount[b * 16], 1u);
                if (m < MBCAP)
                    mlist[(size_t)b * MBCAP + m] = make_int2((int)leader, idx);
            }
        }
    }
    int s = (int)((x * 0x01010101u) >> 24);            // byte-sum (each byte 0/1)
    #pragma unroll
    for (int off = 32; off; off >>= 1) s += __shfl_down(s, off);
    if (lane == 0) tileSum[b * TILES_PAD + tile] = s;
}

// ---------------- K4: shuffle-scans + leader full-row writes + slotOf ----------------
// Scan A (469 tile sums) and scan B (in-tile rank) via 64-wide shuffle scans:
// 3 barriers total (was 32 LDS-ladder barriers). Full 160B rows, cached
// stores (contiguous ~35KB/tile regions, L2-combined; clean 58 MB write).
__global__ void k_finish(const float* __restrict__ pts, const int* __restrict__ lid32,
                         const unsigned char* __restrict__ flag,
                         const int* __restrict__ tileSum,
                         float* __restrict__ out, unsigned short* __restrict__ slotOf) {
    int b = blockIdx.x & 7;
    int tile = blockIdx.x >> 3;
    int t = threadIdx.x;

    __shared__ int wsumA[4];
    __shared__ int wsumB[4];
    __shared__ int soff[TILES_PAD];
    // --- scan A: exclusive scan over 256 pairs of tile sums ---
    int v0 = (2 * t     < TILES) ? tileSum[b * TILES_PAD + 2 * t]     : 0;
    int v1 = (2 * t + 1 < TILES) ? tileSum[b * TILES_PAD + 2 * t + 1] : 0;
    int w = v0 + v1;
    int e = block_scan_excl(w, t, wsumA);      // 1 barrier inside
    soff[2 * t] = e;
    soff[2 * t + 1] = e + v0;

    // --- scan B: in-tile leader rank from flag ---
    int idx = tile * 256 + t;
    int g = b * NPB + idx;
    int f = (idx < NPB) ? (int)flag[g] : 0;
    __syncthreads();                           // wsumA reuse guard + soff publish (pre-scan)
    int rank = block_scan_excl(f, t, wsumB);   // 1 barrier inside (also covers soff)

    if (idx >= NPB || !f) return;              // leaders only

    int slot = soff[tile] + rank;
    slotOf[g] = (unsigned short)(slot < 65535 ? slot : 65535);  // before clip!
    if (slot >= MAX_VOX) return;
    int lid = lid32[g];
    unsigned ul = (unsigned)lid;
    unsigned cx = ul % (unsigned)GX;
    unsigned tt = ul / (unsigned)GX;
    unsigned cy = tt % (unsigned)GY;
    unsigned cz = tt / (unsigned)GY;
    long long r = (long long)b * MAX_VOX + slot;
    ((float4*)(out + OUT_COOR))[r] = make_float4((float)b, (float)cz, (float)cy, (float)cx);
    out[OUT_NUM + r] = 1.f;                    // multi corrected by k_multi
    const float* p = pts + (long long)g * 5;
    float4* row = (float4*)(out + OUT_VOX) + (size_t)r * MAX_PTS;
    row[0] = make_float4(p[1], p[2], p[3], p[4]);
    float4 zf = make_float4(0.f, 0.f, 0.f, 0.f);
    #pragma unroll
    for (int i = 1; i < MAX_PTS; i++) row[i] = zf;
}

// ---------------- K5: rank + scatter multi-cell non-leaders; fix num ----------------
__global__ void k_multi(const float* __restrict__ pts,
                        const int2* __restrict__ mlist, const unsigned* __restrict__ mcount,
                        const unsigned short* __restrict__ slotOf,
                        float* __restrict__ out) {
    int b = blockIdx.y;
    unsigned n = mcount[b * 16];
    if (n > MBCAP) n = MBCAP;
    unsigned t = blockIdx.x * blockDim.x + threadIdx.x;
    const int2* lst = mlist + (size_t)b * MBCAP;
    bool active = (t < n);
    int2 e = active ? lst[t] : make_int2(-1, -1);   // (leaderIdx, idx)
    int pos = 1;                                    // leader (not in list) is pos 0
    int same = 0;                                   // same-cell entries incl. self
    __shared__ int2 sm[MTILE];
    for (unsigned chunk = 0; chunk < n; chunk += MTILE) {
        unsigned m = n - chunk;
        if (m > MTILE) m = MTILE;
        for (unsigned i = threadIdx.x; i < m; i += 256)
            sm[i] = lst[chunk + i];
        __syncthreads();
        if (active) {
            #pragma unroll 4
            for (unsigned j = 0; j < m; j++) {
                int2 o = sm[j];
                if (o.x == e.x) { same++; if (o.y < e.y) pos++; }
            }
        }
        __syncthreads();
    }
    if (!active) return;
    int slot = (int)slotOf[(size_t)b * NPB + e.x];
    if (slot >= MAX_VOX) return;
    if (pos == 1) {                                 // smallest non-leader writes true count
        int cnt = same + 1;                         // + leader
        out[OUT_NUM + (long long)b * MAX_VOX + slot] =
            (float)(cnt < MAX_PTS ? cnt : MAX_PTS);
    }
    if (pos >= MAX_PTS) return;
    const float* p = pts + ((long long)b * NPB + e.y) * 5;
    ((float4*)(out + OUT_VOX))[(long long)(b * MAX_VOX + slot) * MAX_PTS + pos] =
        make_float4(p[1], p[2], p[3], p[4]);
}

extern "C" void kernel_launch(void* const* d_in, const int* in_sizes, int n_in,
                              void* d_out, int out_size, void* d_ws, size_t ws_size,
                              hipStream_t stream) {
    const float* pts = (const float*)d_in[0];
    float* out = (float*)d_out;

    char* w = (char*)d_ws;
    unsigned* tbl0 = (unsigned*)w;            w += (size_t)NB * T0 * 4;    // 16 MB (no init)
    unsigned long long* slabB = (unsigned long long*)w;
    w += (size_t)NSLOT2 * 8;                                               // 2 MB
    int2* mlist = (int2*)w;  w += (size_t)NB * MBCAP * 8;                  // 0.5 MB
    int* lid32 = (int*)w;    w += (size_t)NPTS * 4;                        // 3.84 MB
    int* tileSum = (int*)w;  w += (size_t)NB * TILES_PAD * 4;              // 16 KB
    unsigned* mcount = (unsigned*)w; w += (size_t)NB * 16 * 4;             // 512 B
    unsigned short* slotOf = (unsigned short*)w; w += (size_t)NPTS * 2;    // 1.92 MB
    unsigned char* flag = (unsigned char*)w;  w += (size_t)NPTS;           // 0.96 MB

    const int PB = TILES * NB;      // 3752 blocks for per-point kernels
    k_init<<<dim3(PB), dim3(256), 0, stream>>>(pts, out, (ulonglong2*)slabB,
                                               tbl0, lid32, mcount);
    k_l0<<<dim3(PB), dim3(256), 0, stream>>>(lid32, tbl0, flag, slabB);
    k_sweep<<<dim3(NSLOT2 / 256), dim3(256), 0, stream>>>(slabB, tbl0, lid32, flag);
    k_count<<<dim3(TILES * NB / 4), dim3(256), 0, stream>>>((const unsigned*)flag, lid32,
                                                            slabB, tbl0,
                                                            tileSum, mlist, mcount);
    k_finish<<<dim3(PB), dim3(256), 0, stream>>>(pts, lid32, flag, tileSum, out, slotOf);
    k_multi<<<dim3(MBCAP / 256, NB), dim3(256), 0, stream>>>(pts, mlist, mcount, slotOf, out);
}